// Round 6
// baseline (787.662 us; speedup 1.0000x reference)
//
#include <hip/hip_runtime.h>
#include <math.h>

// CapsuleLayer dynamic routing, fused. R12 = R10's Phase A (MB=1, packed
// wave-linear W, pri[9] float4 in AGPRs, direct-x) + restructured Phase B:
//   - logits in REGISTERS (lg[9], replicated across og-quad by the shfl dot
//     reduce) — no LDS logit array, no LDS logit passes.
//   - no max-subtraction (|logit| <= ~42 bound => exp <= 1.7e18, safe in fp32)
//   - sumexp fused into the s-loop (s unnormalized, divide by D after)
// => 2 barriers/iter (5 total) vs R10's ~18. R11 lesson: W-byte halving is
// NOT the lever (R7/R9/R10 all ~75-92 us regardless of W traffic); R10's
// floor is Phase B's barrier-serialized softmax structure.
// waves_per_eu(5): budget ~102 >= ~90 demand (36 acc pri + 9 lg + arch),
// no spill (R8/R9/R11 spill scars), ~5 waves/EU.

#define NBATCH 256
#define NC 10
#define NR 1152
#define IC 8
#define OC 16
#define NITER 3
#define T 512
#define RPT 9    // NR / 128 r-values per thread
#define WP_F4 (NC * RPT * 8 * T)   // 368640 float4 = 5.9 MB packed W

// ---------------------------------------------------------------------------
// Repack W[c][r][i][o] (float4 granularity: idx ((c*NR+r)*IC+i)*4+og) into
// wave-linear Wp[((c*9+p)*8+k)*512 + t] = W[c][(t>>2)+128p][k][og=t&3].
// Main-kernel load (p,k) reads Wp at base + (p*8+k)*512 + t: a wave reads
// 64 consecutive float4s = 1 KB contiguous = 8 full 128B lines.
// ---------------------------------------------------------------------------
__global__ __launch_bounds__(256)
void repack_w(const float4* __restrict__ W4, float4* __restrict__ Wp) {
    int j = blockIdx.x * 256 + threadIdx.x;      // ((c*9+p)*8+k)*512 + t
    int t  = j & 511;
    int pk = (j >> 9) % 72;
    int c  = (j >> 9) / 72;
    int p  = pk >> 3, k = pk & 7;
    int r  = (t >> 2) + (p << 7);
    int og = t & 3;
    Wp[j] = W4[(((size_t)c * NR + r) * IC + k) * 4 + og];
}

__device__ __forceinline__ float wave_sum(float v) {
#pragma unroll
    for (int m = 1; m <= 32; m <<= 1) v += __shfl_xor(v, m, 64);
    return v;
}

template <bool PACKED>
__global__ __launch_bounds__(T)
__attribute__((amdgpu_waves_per_eu(5)))   // budget ~102 >= ~90 demand: no spill
void caps_route(
    const float* __restrict__ x,   // [B, NR, IC]
    const float4* __restrict__ Wg, // PACKED ? Wp : W (as float4)
    float* __restrict__ out)       // [B, NC, OC]
{
    __shared__ float red[128];     // 8 waves x 16 outputs (unnormalized s)
    __shared__ float sred[8];      // 8 wave partials of sum(exp) (x4 og over-count)
    __shared__ float vout[OC];

    const int t    = threadIdx.x;
    const int og   = t & 3;        // o-quad (o = og*4+j)
    const int rr   = t >> 2;       // 0..127
    const int lane = t & 63;
    const int wid  = t >> 6;       // 0..7

    const int c = blockIdx.x >> 8;     // c-major: 256 consecutive blocks share W[c]
    const int b = blockIdx.x & 255;

    // ---------------- Phase A: pri[p] for r=rr+128p, o-quad og --------------
    float4 pri[RPT];
    const float4* __restrict__ xg = (const float4*)(x + (size_t)b * (NR * IC));

    if (PACKED) {
        const float4* __restrict__ wp = Wg + (size_t)c * (RPT * 8 * T) + t;
#pragma unroll
        for (int p = 0; p < RPT; ++p) {
            const int r = rr + (p << 7);
            float4 xa = xg[2 * r], xc = xg[2 * r + 1];   // og-quad broadcast
            float xv[8] = {xa.x, xa.y, xa.z, xa.w, xc.x, xc.y, xc.z, xc.w};
            float4 a = make_float4(0.f, 0.f, 0.f, 0.f);
#pragma unroll
            for (int k = 0; k < 8; ++k) {
                float4 w = wp[(p * 8 + k) * T];          // 1 KB contiguous/wave
                a.x = fmaf(xv[k], w.x, a.x);
                a.y = fmaf(xv[k], w.y, a.y);
                a.z = fmaf(xv[k], w.z, a.z);
                a.w = fmaf(xv[k], w.w, a.w);
            }
            pri[p] = a;
        }
    } else {
        const float4* __restrict__ wb = Wg + (size_t)c * (NR * IC * 4);
#pragma unroll
        for (int p = 0; p < RPT; ++p) {
            const int r = rr + (p << 7);
            float4 xa = xg[2 * r], xc = xg[2 * r + 1];
            float xv[8] = {xa.x, xa.y, xa.z, xa.w, xc.x, xc.y, xc.z, xc.w};
            const float4* wp = wb + (size_t)r * 32 + og;
            float4 a = make_float4(0.f, 0.f, 0.f, 0.f);
#pragma unroll
            for (int k = 0; k < 8; ++k) {
                float4 w = wp[k * 4];
                a.x = fmaf(xv[k], w.x, a.x);
                a.y = fmaf(xv[k], w.y, a.y);
                a.z = fmaf(xv[k], w.z, a.z);
                a.w = fmaf(xv[k], w.w, a.w);
            }
            pri[p] = a;
        }
    }

    // ---------------- Phase B: 3 routing iterations, logits in registers ----
    float lg[RPT];
#pragma unroll
    for (int k = 0; k < RPT; ++k) lg[k] = 0.f;

    for (int it = 0; it < NITER; ++it) {
        const bool uni = (it == 0);  // softmax of zeros = uniform

        // weights e[k] = exp(logit) (no max-subtract; |logit|<=~42 bound)
        float e[RPT];
        float lsum = 0.f;
        if (uni) {
#pragma unroll
            for (int k = 0; k < RPT; ++k) e[k] = 1.f;
            lsum = (float)RPT;
        } else {
#pragma unroll
            for (int k = 0; k < RPT; ++k) { e[k] = __expf(lg[k]); lsum += e[k]; }
        }
        // wave-level D partial (each r counted 4x across the og quad)
        lsum = wave_sum(lsum);
        if (lane == 0) sred[wid] = lsum;

        // unnormalized s[o] partials
        float4 s = make_float4(0.f, 0.f, 0.f, 0.f);
#pragma unroll
        for (int k = 0; k < RPT; ++k) {
            s.x = fmaf(e[k], pri[k].x, s.x);
            s.y = fmaf(e[k], pri[k].y, s.y);
            s.z = fmaf(e[k], pri[k].z, s.z);
            s.w = fmaf(e[k], pri[k].w, s.w);
        }
        // reduce over the 16 rr slots (same og) within each wave
#pragma unroll
        for (int msk = 4; msk <= 32; msk <<= 1) {
            s.x += __shfl_xor(s.x, msk, 64);
            s.y += __shfl_xor(s.y, msk, 64);
            s.z += __shfl_xor(s.z, msk, 64);
            s.w += __shfl_xor(s.w, msk, 64);
        }
        if (lane < 4) ((float4*)red)[wid * 4 + og] = s;  // red[wid*16+o]
        __syncthreads();                                  // sync1

        if (t < OC) {
            float sv = 0.f, Draw = 0.f;
#pragma unroll
            for (int w = 0; w < 8; ++w) { sv += red[w * 16 + t]; Draw += sred[w]; }
            sv *= 4.0f / Draw;            // Draw = 4 * sum_r e_r (og over-count)
            float sq = sv * sv;
#pragma unroll
            for (int msk = 1; msk <= 8; msk <<= 1) sq += __shfl_xor(sq, msk, 64);
            float v = sv * (sqrtf(sq) / (1.0f + sq)); // squash
            if (it == NITER - 1) out[((size_t)b * NC + c) * OC + t] = v;
            else vout[t] = v;
        }

        if (it < NITER - 1) {
            __syncthreads();              // sync2: vout visible
            float4 v4 = ((const float4*)vout)[og];
#pragma unroll
            for (int k = 0; k < RPT; ++k) {
                float d = pri[k].x * v4.x + pri[k].y * v4.y +
                          pri[k].z * v4.z + pri[k].w * v4.w;
                d += __shfl_xor(d, 1, 64);   // sum the 4 og partials ->
                d += __shfl_xor(d, 2, 64);   // all 4 lanes hold full dot
                lg[k] += d;
            }
        }
    }
}

extern "C" void kernel_launch(void* const* d_in, const int* in_sizes, int n_in,
                              void* d_out, int out_size, void* d_ws, size_t ws_size,
                              hipStream_t stream) {
    const float* x = (const float*)d_in[0];
    const float* W = (const float*)d_in[1];
    float* out = (float*)d_out;
    const size_t wp_bytes = (size_t)WP_F4 * sizeof(float4);  // 5,898,240 B
    if (d_ws != nullptr && ws_size >= wp_bytes) {
        repack_w<<<dim3(WP_F4 / 256), dim3(256), 0, stream>>>(
            (const float4*)W, (float4*)d_ws);
        caps_route<true><<<dim3(NC * NBATCH), dim3(T), 0, stream>>>(
            x, (const float4*)d_ws, out);
    } else {
        caps_route<false><<<dim3(NC * NBATCH), dim3(T), 0, stream>>>(
            x, (const float4*)W, out);
    }
}

// Round 7
// 632.188 us; speedup vs baseline: 1.2459x; 1.2459x over previous
//
#include <hip/hip_runtime.h>
#include <math.h>

// CapsuleLayer dynamic routing, fused. R13 = R12 structure (register logits,
// no max-pass, fused sumexp, 2 barriers/iter) with the spill fixed:
//   - e[] array ELIMINATED (exp computed inline in the s-loop) — persistent
//     Phase-B state is lg[9] only. Demand ~= 36 acc + 9 lg + ~44 arch = ~89.
//   - waves_per_eu(4,4): 128-reg budget, 39 regs headroom — no-spill by
//     arithmetic. 4 waves/EU (50%).
// R12 post-mortem: (5)-clamp budget ~96 < demand ~110 -> wholesale spill
// (WRITE 1.42 GB, 738 us). Third repeat of the spill failure mode (R8/R9/R11):
// never raise register demand while tightening the clamp.
// Phase A unchanged from R10 (MB=1, wave-linear packed W, direct-x).

#define NBATCH 256
#define NC 10
#define NR 1152
#define IC 8
#define OC 16
#define NITER 3
#define T 512
#define RPT 9    // NR / 128 r-values per thread
#define WP_F4 (NC * RPT * 8 * T)   // 368640 float4 = 5.9 MB packed W

// ---------------------------------------------------------------------------
// Repack W[c][r][i][o] (float4 granularity: idx ((c*NR+r)*IC+i)*4+og) into
// wave-linear Wp[((c*9+p)*8+k)*512 + t] = W[c][(t>>2)+128p][k][og=t&3].
// Main-kernel load (p,k) reads Wp at base + (p*8+k)*512 + t: a wave reads
// 64 consecutive float4s = 1 KB contiguous = 8 full 128B lines.
// ---------------------------------------------------------------------------
__global__ __launch_bounds__(256)
void repack_w(const float4* __restrict__ W4, float4* __restrict__ Wp) {
    int j = blockIdx.x * 256 + threadIdx.x;      // ((c*9+p)*8+k)*512 + t
    int t  = j & 511;
    int pk = (j >> 9) % 72;
    int c  = (j >> 9) / 72;
    int p  = pk >> 3, k = pk & 7;
    int r  = (t >> 2) + (p << 7);
    int og = t & 3;
    Wp[j] = W4[(((size_t)c * NR + r) * IC + k) * 4 + og];
}

__device__ __forceinline__ float wave_sum(float v) {
#pragma unroll
    for (int m = 1; m <= 32; m <<= 1) v += __shfl_xor(v, m, 64);
    return v;
}

template <bool PACKED>
__global__ __launch_bounds__(T)
__attribute__((amdgpu_waves_per_eu(4, 4)))   // 128-reg budget >> ~89 demand: no spill
void caps_route(
    const float* __restrict__ x,   // [B, NR, IC]
    const float4* __restrict__ Wg, // PACKED ? Wp : W (as float4)
    float* __restrict__ out)       // [B, NC, OC]
{
    __shared__ float red[128];     // 8 waves x 16 outputs (unnormalized s)
    __shared__ float sred[8];      // 8 wave partials of sum(exp) (x4 og over-count)
    __shared__ float vout[OC];

    const int t    = threadIdx.x;
    const int og   = t & 3;        // o-quad (o = og*4+j)
    const int rr   = t >> 2;       // 0..127
    const int lane = t & 63;
    const int wid  = t >> 6;       // 0..7

    const int c = blockIdx.x >> 8;     // c-major: 256 consecutive blocks share W[c]
    const int b = blockIdx.x & 255;

    // ---------------- Phase A: pri[p] for r=rr+128p, o-quad og --------------
    float4 pri[RPT];
    const float4* __restrict__ xg = (const float4*)(x + (size_t)b * (NR * IC));

    if (PACKED) {
        const float4* __restrict__ wp = Wg + (size_t)c * (RPT * 8 * T) + t;
#pragma unroll
        for (int p = 0; p < RPT; ++p) {
            const int r = rr + (p << 7);
            float4 xa = xg[2 * r], xc = xg[2 * r + 1];   // og-quad broadcast
            float xv[8] = {xa.x, xa.y, xa.z, xa.w, xc.x, xc.y, xc.z, xc.w};
            float4 a = make_float4(0.f, 0.f, 0.f, 0.f);
#pragma unroll
            for (int k = 0; k < 8; ++k) {
                float4 w = wp[(p * 8 + k) * T];          // 1 KB contiguous/wave
                a.x = fmaf(xv[k], w.x, a.x);
                a.y = fmaf(xv[k], w.y, a.y);
                a.z = fmaf(xv[k], w.z, a.z);
                a.w = fmaf(xv[k], w.w, a.w);
            }
            pri[p] = a;
        }
    } else {
        const float4* __restrict__ wb = Wg + (size_t)c * (NR * IC * 4);
#pragma unroll
        for (int p = 0; p < RPT; ++p) {
            const int r = rr + (p << 7);
            float4 xa = xg[2 * r], xc = xg[2 * r + 1];
            float xv[8] = {xa.x, xa.y, xa.z, xa.w, xc.x, xc.y, xc.z, xc.w};
            const float4* wp = wb + (size_t)r * 32 + og;
            float4 a = make_float4(0.f, 0.f, 0.f, 0.f);
#pragma unroll
            for (int k = 0; k < 8; ++k) {
                float4 w = wp[k * 4];
                a.x = fmaf(xv[k], w.x, a.x);
                a.y = fmaf(xv[k], w.y, a.y);
                a.z = fmaf(xv[k], w.z, a.z);
                a.w = fmaf(xv[k], w.w, a.w);
            }
            pri[p] = a;
        }
    }

    // ---------------- Phase B: 3 routing iterations, logits in registers ----
    float lg[RPT];
#pragma unroll
    for (int k = 0; k < RPT; ++k) lg[k] = 0.f;

    for (int it = 0; it < NITER; ++it) {
        const bool uni = (it == 0);  // softmax of zeros = uniform

        // fused: e = exp(lg[k]) consumed immediately; no e[] array.
        // (no max-subtract: |lg| <= ~60 worst case => exp <= ~1e26, fp32-safe)
        float lsum = 0.f;
        float4 s = make_float4(0.f, 0.f, 0.f, 0.f);
#pragma unroll
        for (int k = 0; k < RPT; ++k) {
            float e = uni ? 1.0f : __expf(lg[k]);
            lsum += e;
            s.x = fmaf(e, pri[k].x, s.x);
            s.y = fmaf(e, pri[k].y, s.y);
            s.z = fmaf(e, pri[k].z, s.z);
            s.w = fmaf(e, pri[k].w, s.w);
        }
        // wave-level D partial (each r counted 4x across the og quad)
        lsum = wave_sum(lsum);
        if (lane == 0) sred[wid] = lsum;

        // reduce s over the 16 rr slots (same og) within each wave
#pragma unroll
        for (int msk = 4; msk <= 32; msk <<= 1) {
            s.x += __shfl_xor(s.x, msk, 64);
            s.y += __shfl_xor(s.y, msk, 64);
            s.z += __shfl_xor(s.z, msk, 64);
            s.w += __shfl_xor(s.w, msk, 64);
        }
        if (lane < 4) ((float4*)red)[wid * 4 + og] = s;  // red[wid*16+o]
        __syncthreads();                                  // sync1

        if (t < OC) {
            float sv = 0.f, Draw = 0.f;
#pragma unroll
            for (int w = 0; w < 8; ++w) { sv += red[w * 16 + t]; Draw += sred[w]; }
            sv *= 4.0f / Draw;            // Draw = 4 * sum_r e_r (og over-count)
            float sq = sv * sv;
#pragma unroll
            for (int msk = 1; msk <= 8; msk <<= 1) sq += __shfl_xor(sq, msk, 64);
            float v = sv * (sqrtf(sq) / (1.0f + sq)); // squash
            if (it == NITER - 1) out[((size_t)b * NC + c) * OC + t] = v;
            else vout[t] = v;
        }

        if (it < NITER - 1) {
            __syncthreads();              // sync2: vout visible
            float4 v4 = ((const float4*)vout)[og];
#pragma unroll
            for (int k = 0; k < RPT; ++k) {
                float d = pri[k].x * v4.x + pri[k].y * v4.y +
                          pri[k].z * v4.z + pri[k].w * v4.w;
                d += __shfl_xor(d, 1, 64);   // sum the 4 og partials ->
                d += __shfl_xor(d, 2, 64);   // all 4 lanes hold full dot
                lg[k] += d;
            }
        }
    }
}

extern "C" void kernel_launch(void* const* d_in, const int* in_sizes, int n_in,
                              void* d_out, int out_size, void* d_ws, size_t ws_size,
                              hipStream_t stream) {
    const float* x = (const float*)d_in[0];
    const float* W = (const float*)d_in[1];
    float* out = (float*)d_out;
    const size_t wp_bytes = (size_t)WP_F4 * sizeof(float4);  // 5,898,240 B
    if (d_ws != nullptr && ws_size >= wp_bytes) {
        repack_w<<<dim3(WP_F4 / 256), dim3(256), 0, stream>>>(
            (const float4*)W, (float4*)d_ws);
        caps_route<true><<<dim3(NC * NBATCH), dim3(T), 0, stream>>>(
            x, (const float4*)d_ws, out);
    } else {
        caps_route<false><<<dim3(NC * NBATCH), dim3(T), 0, stream>>>(
            x, (const float4*)W, out);
    }
}